// Round 12
// baseline (213.065 us; speedup 1.0000x reference)
//
#include <hip/hip_runtime.h>
#include <math.h>

// ETM forward. B=1024 S=512 V=50000 E=300 H=800 T=50.  4 launches:
// kbA: blocks [0,FRAGB): frag builders, SOURCE-COALESCED reads + scatter
//        writes (r10: stride-3200B gather reads, 64 lines/load) run FIRST.
//      blocks [FRAGB,FRAGB+K4B): cast+beta tile (XCD-affine): NT rho f32 ->
//        bf16 LDS -> MFMA with alpha frags HOISTED to regs (bvv[10], clamped
//        row, branch-minimal -> compiler can prefetch; r10 kept loads
//        in-loop at VGPR=20) -> betaU + rhoh + topicsumT[t][tile].
// kb1: sliced token gather (slice r == XCD r, L2-warm rhoh) -> xbarP;
//      64 appended blocks reduce topicsumT -> topicsum (parallel, r10 fix).
// ktail: [kx+k2m+k3] per 16 docs (64 blocks).
// k6: recon + loss.
// r11 fix: __builtin_nontemporal_load needs a NATIVE vector type, not
// HIP_vector_type float4 -> load via ext_vector_type(4) float.

#define Bn 1024
#define Sn 512
#define Vn 50000
#define En 300
#define Hn 800
#define Tn 50
#define KP 320             // padded K for E-dim (10 tiles of 32)
#define BSTR 64            // betaU bf16 row stride (ushorts) = 128 B
#define W1FRAG_N (50 * 10 * 64 * 8)     // 256000
#define WFRAG_N  (8 * 25 * 64 * 8)      // 102400
#define NRANGE 8
#define K4B 3128                         // 8 x 391 (3125 tiles + 3 idle)
#define NTILE 3125
#define NTILEP 3136                      // padded tile stride (floats)
#define FRAGB 1400                       // 1400*256 = 358400 = exact partition
#define GB (Bn * NRANGE)                 // 8192 gather blocks

typedef __bf16 bf16x8 __attribute__((ext_vector_type(8)));
typedef float  f32x4  __attribute__((ext_vector_type(4)));
typedef float  f32x2  __attribute__((ext_vector_type(2)));
typedef float  f32v4  __attribute__((ext_vector_type(4)));   // native, NT-loadable

__device__ __forceinline__ float waveReduceSum(float v) {
    #pragma unroll
    for (int off = 32; off > 0; off >>= 1) v += __shfl_xor(v, off, 64);
    return v;
}
__device__ __forceinline__ float waveReduceMax(float v) {
    #pragma unroll
    for (int off = 32; off > 0; off >>= 1) v = fmaxf(v, __shfl_xor(v, off, 64));
    return v;
}
__device__ __forceinline__ unsigned short f2bf(float x) {
    unsigned u = __float_as_uint(x);
    return (unsigned short)((u + 0x7FFFu + ((u >> 16) & 1u)) >> 16);
}
__device__ __forceinline__ float bf_lo(unsigned u) { return __uint_as_float(u << 16); }
__device__ __forceinline__ float bf_hi(unsigned u) { return __uint_as_float(u & 0xFFFF0000u); }
__device__ __forceinline__ int lane_prefix(unsigned long long m) {
    return __builtin_amdgcn_mbcnt_hi((unsigned)(m >> 32),
           __builtin_amdgcn_mbcnt_lo((unsigned)m, 0));
}
__device__ __forceinline__ bf16x8 pack8v(f32v4 a, f32v4 b) {
    union { bf16x8 v; unsigned short s[8]; } u;
    u.s[0] = f2bf(a.x); u.s[1] = f2bf(a.y); u.s[2] = f2bf(a.z); u.s[3] = f2bf(a.w);
    u.s[4] = f2bf(b.x); u.s[5] = f2bf(b.y); u.s[6] = f2bf(b.z); u.s[7] = f2bf(b.w);
    return u.v;
}

#define PKACC(u) { \
    c0 += (f32x2){bf_lo((u).x), bf_hi((u).x)}; \
    c1 += (f32x2){bf_lo((u).y), bf_hi((u).y)}; \
    c2 += (f32x2){bf_lo((u).z), bf_hi((u).z)}; \
    c3 += (f32x2){bf_lo((u).w), bf_hi((u).w)}; }

// kbA: frag builders (blocks < FRAGB, coalesced) + cast+beta tiles.
__global__ __launch_bounds__(256) void kbA_beta(
        const float* __restrict__ rho, const float* __restrict__ alpha,
        const float* __restrict__ W1, const float* __restrict__ Wmu,
        const float* __restrict__ Wlv, unsigned short* __restrict__ rhoh,
        unsigned int* __restrict__ betaU32, float* __restrict__ topicsumT,
        unsigned short* __restrict__ w1frag, unsigned short* __restrict__ wfrag) {
    __shared__ __align__(16) unsigned short xs[16 * 328];   // 10496 B
    __shared__ unsigned short trans[16 * 66];               // 2112 B
    const int tid = threadIdx.x;
    if (blockIdx.x < FRAGB) {
        // ---- frag builders: source-coalesced reads, scatter writes ----
        const int gid = blockIdx.x * 256 + tid;       // < 358400 exactly
        if (gid < 240000) {
            // w1 main: L = e*800 + hcol (coalesced read of W1)
            const int e = gid / Hn, hcol = gid - e * Hn;
            const int kt = e >> 5, rem = e & 31;
            const int quad = rem >> 3, j = rem & 7;
            const int nt = hcol >> 4, l15 = hcol & 15;
            w1frag[((nt * 10 + kt) * 64 + quad * 16 + l15) * 8 + j] = f2bf(W1[gid]);
        } else if (gid < 256000) {
            // w1 pad (e in [300,320)): zero
            const int p = gid - 240000;               // < 16000
            const int nt = p / 320, q = p - nt * 320;
            const int ei = q >> 4, l15 = q & 15;
            const int rem = 12 + ei;                  // e-288
            const int quad = rem >> 3, j = rem & 7;
            w1frag[((nt * 10 + 9) * 64 + quad * 16 + l15) * 8 + j] = 0;
        } else if (gid < 336000) {
            // wfrag main: L = src*40000 + k*50 + t (coalesced Wmu/Wlv read)
            const int L = gid - 256000;
            const int src = L / 40000, LL = L - src * 40000;
            const int k = LL / Tn, t = LL - k * Tn;
            const int kt = k >> 5, rem = k & 31;
            const int quad = rem >> 3, j = rem & 7;
            const int nt = (t >> 4) + (src ? 4 : 0), l15 = t & 15;
            wfrag[((nt * 25 + kt) * 64 + quad * 16 + l15) * 8 + j] =
                f2bf(src ? Wlv[LL] : Wmu[LL]);
        } else {
            // wfrag pad (t >= 50): zero
            const int p = gid - 336000;               // < 22400
            const int half = p / 11200, q = p - half * 11200;
            const int nt = half ? 7 : 3;
            const int kt = q / 448, qq = q - kt * 448;
            const int quad = qq / 112, r2 = qq - quad * 112;
            const int l15 = 2 + (r2 >> 3), j = r2 & 7;
            wfrag[((nt * 25 + kt) * 64 + quad * 16 + l15) * 8 + j] = 0;
        }
        return;
    }
    // ---- tile: cast + beta ----
    const int bx = blockIdx.x - FRAGB;       // FRAGB%8==0 -> XCD = blockIdx%8
    const int x = blockIdx.x & 7;            // XCD == slice
    const int n = bx >> 3;                   // 0..390
    const int tile = ((x * 3125) >> 3) + n;
    if (tile >= (((x + 1) * 3125) >> 3)) return;
    const int wave = tid >> 6, lane = tid & 63;
    const int quad = lane >> 4, l15 = lane & 15;
    const int v0 = tile * 16;
    for (int i = tid; i < 16 * 80; i += 256) {      // 80 float4-slots/row
        int row = i / 80, s4 = i - row * 80;
        ushort4 o = {0, 0, 0, 0};
        if (s4 < 75) {
            f32v4 r = __builtin_nontemporal_load(
                (const f32v4*)(rho + (size_t)(v0 + row) * En + s4 * 4));
            o.x = f2bf(r.x); o.y = f2bf(r.y); o.z = f2bf(r.z); o.w = f2bf(r.w);
        }
        *(ushort4*)&xs[row * 328 + s4 * 4] = o;
    }
    // hoist alpha fragments to registers while rho staging is in flight:
    // clamped topic row (garbage topics 50..63 land in unread slots),
    // branch-minimal so the compiler can prefetch all loads.
    const int tA = 16 * wave + l15;
    const int tAc = (tA < Tn) ? tA : (Tn - 1);
    const float* arowA = alpha + (size_t)tAc * En;
    bf16x8 bvv[10];
    #pragma unroll
    for (int kt = 0; kt < 10; ++kt) {
        const int e0 = kt * 32 + quad * 8;           // <= 312
        f32v4 f0 = {0.f, 0.f, 0.f, 0.f}, f1 = {0.f, 0.f, 0.f, 0.f};
        if (e0 + 8 <= En) {
            f0 = *(const f32v4*)(arowA + e0);
            f1 = *(const f32v4*)(arowA + e0 + 4);
        } else if (e0 < En) {
            f0 = *(const f32v4*)(arowA + e0);
        }
        bvv[kt] = pack8v(f0, f1);
    }
    __syncthreads();
    // persist bf16 tile (write-allocates this XCD's L2 slice for kb1)
    for (int i = tid; i < 16 * 40; i += 256) {
        int row = i / 40, c8 = (i - row * 40) * 8;
        *(uint4*)(rhoh + (size_t)(v0 + row) * KP + c8) = *(const uint4*)&xs[row * 328 + c8];
    }
    // betaU tile: tight MFMA chain, B operands already in registers
    const unsigned short* arow = xs + l15 * 328 + quad * 8;
    f32x4 acc = {0.f, 0.f, 0.f, 0.f};
    #pragma unroll
    for (int kt = 0; kt < 10; ++kt) {
        bf16x8 a = *(const bf16x8*)(arow + kt * 32);
        acc = __builtin_amdgcn_mfma_f32_16x16x32_bf16(a, bvv[kt], acc, 0, 0, 0);
    }
    float ts = 0.f;
    #pragma unroll
    for (int r = 0; r < 4; ++r) {
        float ev = expf(acc[r]);
        ts += ev;
        trans[(quad * 4 + r) * 66 + 16 * wave + l15] = f2bf(ev);
    }
    ts += __shfl_xor(ts, 16, 64);
    ts += __shfl_xor(ts, 32, 64);
    const int t = 16 * wave + l15;
    if (lane < 16)
        topicsumT[(size_t)t * NTILEP + tile] = ts;   // transposed, non-atomic
    __syncthreads();
    unsigned int* dst = betaU32 + (size_t)v0 * 32;
    const unsigned int* tr32 = (const unsigned int*)trans;
    for (int i = tid; i < 16 * 32; i += 256)
        dst[i] = tr32[(i >> 5) * 33 + (i & 31)];
}

// kb1: sliced token gather (blocks < GB) + topicsum reduction (64 appended).
__global__ __launch_bounds__(256) void kb1_gather(
        const unsigned short* __restrict__ rhoh, const int* __restrict__ ids,
        int* __restrict__ toks, int* __restrict__ cnt,
        float* __restrict__ xbarP, const float* __restrict__ topicsumT,
        float* __restrict__ topicsum, float* __restrict__ loss) {
    __shared__ __align__(16) int sid[Sn];
    __shared__ int sfid[Sn];
    __shared__ __align__(16) float xred[4][320];
    __shared__ int scount, sfull;
    const int tid = threadIdx.x;
    const int wave = tid >> 6, lane = tid & 63;
    if (blockIdx.x >= GB) {
        // ---- parallel topicsum reduction: one block per topic slot t ----
        const int t = blockIdx.x - GB;               // 0..63
        float s = 0.f;
        const float* row = topicsumT + (size_t)t * NTILEP;
        for (int i = tid; i < NTILE; i += 256) s += row[i];
        s = waveReduceSum(s);
        float* red = (float*)xred;
        if (lane == 0) red[wave] = s;
        __syncthreads();
        if (tid == 0) topicsum[t] = red[0] + red[1] + red[2] + red[3];
        if (blockIdx.x == GB && tid == 1) *loss = 0.f;
        return;
    }
    const int r = blockIdx.x & (NRANGE - 1), b = blockIdx.x >> 3;
    const int lo = ((r * 3125) >> 3) * 16;
    const int hi = (((r + 1) * 3125) >> 3) * 16;
    if (tid == 0) { scount = 0; sfull = 0; }
    __syncthreads();
    #pragma unroll
    for (int s0 = 0; s0 < Sn; s0 += 256) {
        int id = __builtin_nontemporal_load(&ids[b * Sn + s0 + tid]);
        bool val = (id != 1 && id != 2);
        bool inr = val && id >= lo && id < hi;
        unsigned long long mb = __ballot(inr);
        int pre = lane_prefix(mb);
        int wc = __popcll(mb);
        int base = 0;
        if (lane == 0 && wc) base = atomicAdd(&scount, wc);
        base = __shfl(base, 0, 64);
        if (inr) sid[base + pre] = id;
        if (r == 0) {
            unsigned long long fb = __ballot(val);
            int fpre = lane_prefix(fb);
            int fwc = __popcll(fb);
            int fbase = 0;
            if (lane == 0 && fwc) fbase = atomicAdd(&sfull, fwc);
            fbase = __shfl(fbase, 0, 64);
            if (val) sfid[fbase + fpre] = id;
        }
    }
    __syncthreads();
    if (r == 0) {
        const int nf = sfull;
        for (int i = tid; i < nf; i += 256) toks[b * Sn + i] = sfid[i];
        if (tid == 0) cnt[b] = nf;
    }
    const int m = scount;
    f32x2 c0 = {0.f, 0.f}, c1 = {0.f, 0.f}, c2 = {0.f, 0.f}, c3 = {0.f, 0.f};
    if (lane < 40) {
        const uint4* rb = (const uint4*)rhoh;
        int s = wave;
        for (; s + 12 < m; s += 16) {
            int i0 = sid[s], i1 = sid[s + 4], i2 = sid[s + 8], i3 = sid[s + 12];
            uint4 u0 = rb[(size_t)i0 * 40 + lane];
            uint4 u1 = rb[(size_t)i1 * 40 + lane];
            uint4 u2 = rb[(size_t)i2 * 40 + lane];
            uint4 u3 = rb[(size_t)i3 * 40 + lane];
            PKACC(u0); PKACC(u1); PKACC(u2); PKACC(u3);
        }
        for (; s < m; s += 4) {
            uint4 u = rb[(size_t)sid[s] * 40 + lane];
            PKACC(u);
        }
        float* xw = &xred[wave][lane * 8];
        *(float4*)(xw)     = (float4){c0[0], c0[1], c1[0], c1[1]};
        *(float4*)(xw + 4) = (float4){c2[0], c2[1], c3[0], c3[1]};
    }
    __syncthreads();
    float* xbp = xbarP + ((size_t)b * NRANGE + r) * KP;
    for (int c = tid; c < KP; c += 256)
        xbp[c] = xred[0][c] + xred[1][c] + xred[2][c] + xred[3][c];
}

// ktail: fused kx+k2m+k3, one block per 16 docs. grid 64.
__global__ __launch_bounds__(256) void ktail(
        const float* __restrict__ xbarP, const int* __restrict__ cnt,
        const unsigned short* __restrict__ w1frag, const float* __restrict__ b1,
        const unsigned short* __restrict__ wfrag,
        const float* __restrict__ bmu, const float* __restrict__ blv,
        float* __restrict__ theta, float* __restrict__ loss) {
    __shared__ unsigned short xs[16 * 328];    // 10496 B
    __shared__ unsigned short hs[16 * 808];    // 25856 B
    __shared__ float mlds[16 * 65];
    __shared__ float llds[16 * 65];
    __shared__ float invn[16];
    const int tid = threadIdx.x;
    const int wave = tid >> 6, lane = tid & 63;
    const int quad = lane >> 4, l15 = lane & 15;
    const int b0 = blockIdx.x * 16;
    if (tid < 16) invn[tid] = 1.0f / (float)cnt[b0 + tid];
    __syncthreads();
    for (int i = tid; i < 16 * (KP / 4); i += 256) {
        int row = i / (KP / 4), e4 = (i - row * (KP / 4)) * 4;
        const float* bp = xbarP + ((size_t)(b0 + row) * NRANGE) * KP + e4;
        float sx = 0.f, sy = 0.f, sz = 0.f, sw_ = 0.f;
        #pragma unroll
        for (int rr = 0; rr < NRANGE; ++rr) {
            float4 v = *(const float4*)(bp + rr * KP);
            sx += v.x; sy += v.y; sz += v.z; sw_ += v.w;
        }
        float in = invn[row];
        ushort4 o;
        o.x = f2bf(sx * in); o.y = f2bf(sy * in);
        o.z = f2bf(sz * in); o.w = f2bf(sw_ * in);
        *(ushort4*)&xs[row * 328 + e4] = o;
    }
    __syncthreads();
    {
        const unsigned short* arow = xs + l15 * 328 + quad * 8;
        for (int nt = wave; nt < 50; nt += 4) {
            f32x4 acc = {0.f, 0.f, 0.f, 0.f};
            #pragma unroll
            for (int kt = 0; kt < 10; ++kt) {
                bf16x8 a = *(const bf16x8*)(arow + kt * 32);
                bf16x8 bv = *(const bf16x8*)(w1frag + ((size_t)(nt * 10 + kt) * 64 + lane) * 8);
                acc = __builtin_amdgcn_mfma_f32_16x16x32_bf16(a, bv, acc, 0, 0, 0);
            }
            const int col = nt * 16 + l15;
            const float bias = b1[col];
            #pragma unroll
            for (int r = 0; r < 4; ++r)
                hs[(quad * 4 + r) * 808 + col] = f2bf(fmaxf(acc[r] + bias, 0.f));
        }
    }
    __syncthreads();
    {
        const unsigned short* arow = hs + l15 * 808 + quad * 8;
        f32x4 am = {0.f, 0.f, 0.f, 0.f}, al = {0.f, 0.f, 0.f, 0.f};
        #pragma unroll
        for (int kt = 0; kt < 25; ++kt) {
            bf16x8 a  = *(const bf16x8*)(arow + kt * 32);
            bf16x8 bm = *(const bf16x8*)(wfrag + ((size_t)(wave * 25 + kt) * 64 + lane) * 8);
            bf16x8 bl = *(const bf16x8*)(wfrag + ((size_t)((4 + wave) * 25 + kt) * 64 + lane) * 8);
            am = __builtin_amdgcn_mfma_f32_16x16x32_bf16(a, bm, am, 0, 0, 0);
            al = __builtin_amdgcn_mfma_f32_16x16x32_bf16(a, bl, al, 0, 0, 0);
        }
        const int t = wave * 16 + l15;
        const float bm_ = (t < Tn) ? bmu[t] : 0.f;
        const float bl_ = (t < Tn) ? blv[t] : 0.f;
        #pragma unroll
        for (int r = 0; r < 4; ++r) {
            int row = quad * 4 + r;
            mlds[row * 65 + t] = am[r] + bm_;
            llds[row * 65 + t] = al[r] + bl_;
        }
    }
    __syncthreads();
    const int tt = (lane < Tn) ? lane : (Tn - 1);
    const bool act = (lane < Tn);
    float klacc = 0.f;
    #pragma unroll
    for (int k = 0; k < 4; ++k) {
        int row = wave * 4 + k;
        float mu = mlds[row * 65 + tt];
        float lv = llds[row * 65 + tt];
        float m = waveReduceMax(act ? mu : -1e30f);
        float ex = act ? expf(mu - m) : 0.f;
        float ssum = waveReduceSum(ex);
        if (act) theta[(b0 + row) * Tn + lane] = ex / ssum;
        klacc += waveReduceSum(act ? (1.f + lv - mu * mu - expf(lv)) : 0.f);
    }
    if (lane == 0) atomicAdd(loss, -0.5f * klacc * (1.0f / (float)Bn));
}

// k6: recon loss. grid Bn.
__global__ __launch_bounds__(256) void k6_recon(
        const int* __restrict__ toks, const int* __restrict__ cnt,
        const float* __restrict__ theta, const float* __restrict__ topicsum,
        const unsigned short* __restrict__ betaUh, float* __restrict__ loss) {
    __shared__ float sw[Tn];
    __shared__ float swred[4];
    const int b = blockIdx.x, tid = threadIdx.x;
    if (tid < Tn) sw[tid] = theta[b * Tn + tid] / topicsum[tid];
    __syncthreads();
    float wr[Tn];
    #pragma unroll
    for (int t = 0; t < Tn; ++t) wr[t] = sw[t];
    float lsum = 0.f;
    const int n = cnt[b];
    for (int i = tid; i < n; i += 256) {
        int v = toks[b * Sn + i];
        const uint4* q = (const uint4*)(betaUh + (size_t)v * BSTR);
        float dot = 0.f;
        #pragma unroll
        for (int k = 0; k < 6; ++k) {
            uint4 u = q[k];
            int t = 8 * k;
            dot += wr[t]     * bf_lo(u.x) + wr[t + 1] * bf_hi(u.x);
            dot += wr[t + 2] * bf_lo(u.y) + wr[t + 3] * bf_hi(u.y);
            dot += wr[t + 4] * bf_lo(u.z) + wr[t + 5] * bf_hi(u.z);
            dot += wr[t + 6] * bf_lo(u.w) + wr[t + 7] * bf_hi(u.w);
        }
        unsigned d = ((const unsigned*)q)[24];
        dot += wr[48] * bf_lo(d) + wr[49] * bf_hi(d);
        lsum += logf(dot + 1e-5f);
    }
    float s = waveReduceSum(lsum);
    const int wave = tid >> 6, lane = tid & 63;
    if (lane == 0) swred[wave] = s;
    __syncthreads();
    if (tid == 0) {
        float tot = swred[0] + swred[1] + swred[2] + swred[3];
        atomicAdd(loss, -tot * (1.0f / (float)Bn));
    }
}

extern "C" void kernel_launch(void* const* d_in, const int* in_sizes, int n_in,
                              void* d_out, int out_size, void* d_ws, size_t ws_size,
                              hipStream_t stream) {
    const int*   ids   = (const int*)d_in[0];
    const float* rho   = (const float*)d_in[1];
    const float* alpha = (const float*)d_in[2];
    const float* W1    = (const float*)d_in[3];
    const float* b1    = (const float*)d_in[4];
    const float* Wmu   = (const float*)d_in[5];
    const float* bmu   = (const float*)d_in[6];
    const float* Wlv   = (const float*)d_in[7];
    const float* blv   = (const float*)d_in[8];

    float* theta = (float*)d_out;            // [B, T]
    float* loss  = theta + Bn * Tn;          // scalar at d_out[51200]

    char* w = (char*)d_ws;
    float* topicsumT = (float*)w;               w += (size_t)64 * NTILEP * 4; // 803KB
    float* topicsum  = (float*)w;               w += 64 * 4;
    unsigned short* w1frag = (unsigned short*)w; w += (size_t)W1FRAG_N * 2;
    unsigned short* wfrag = (unsigned short*)w;  w += (size_t)WFRAG_N * 2;
    int*   cnt      = (int*)w;                  w += Bn * 4;
    int*   toks     = (int*)w;                  w += Bn * Sn * 4;
    float* xbarP    = (float*)w;                w += (size_t)Bn * NRANGE * KP * 4; // 10.5 MB
    unsigned short* rhoh = (unsigned short*)w;  w += (size_t)Vn * KP * 2;   // 32 MB
    unsigned int* betaU32 = (unsigned int*)w;   w += (size_t)Vn * 128;      // 6.4 MB

    kbA_beta<<<FRAGB + K4B, 256, 0, stream>>>(
        rho, alpha, W1, Wmu, Wlv, rhoh, betaU32, topicsumT, w1frag, wfrag);
    kb1_gather<<<GB + 64, 256, 0, stream>>>(rhoh, ids, toks, cnt, xbarP,
                                            topicsumT, topicsum, loss);
    ktail<<<64, 256, 0, stream>>>(xbarP, cnt, w1frag, b1, wfrag, bmu, blv,
                                  theta, loss);
    k6_recon<<<Bn, 256, 0, stream>>>(toks, cnt, theta, topicsum,
                                     (const unsigned short*)betaU32, loss);
}

// Round 13
// 202.496 us; speedup vs baseline: 1.0522x; 1.0522x over previous
//
#include <hip/hip_runtime.h>
#include <math.h>

// ETM forward. B=1024 S=512 V=50000 E=300 H=800 T=50.
// r13 = verbatim restore of r8 (best measured: 199.83us). Post-r8 deltas
// (4-launch fusion, in-reg alpha frags, parallel topicsum) all measured
// neutral-to-harmful; r8's top-5 = harness 256MiB poison fills (~41-43us,
// fixed), every kernel of ours below that line.
// ka2: zero topicsumR/loss + build alpha/W1/[Wmu|Wlv] MFMA B-frags (tiny)
// kb4: [fused cast+beta] per 16-vocab tile: load rho f32 -> bf16 LDS ->
//      MFMA betaU=exp(rhoh@alpha^T) + write rhoh slice. XCD-affine
//      (slice x on XCD x) so each XCD's L2 holds its 4MB rhoh slice warm.
// kb1: sliced token gather (slice r == XCD r, L2-warm rhoh), ballot
//      compaction, plain wave-token-parallel row loads -> xbarP partials.
// ktail: [kx+k2m+k3] per 16 docs: reduce xbarP -> x LDS -> h=relu(x@W1+b1)
//      LDS -> mu/lv MFMA -> softmax/theta/kl.
// k6: recon + loss.

#define Bn 1024
#define Sn 512
#define Vn 50000
#define En 300
#define Hn 800
#define Tn 50
#define KP 320             // padded K for E-dim (10 tiles of 32)
#define BSTR 64            // betaU bf16 row stride (ushorts) = 128 B
#define W1FRAG_N (50 * 10 * 64 * 8)
#define WFRAG_N  (8 * 25 * 64 * 8)
#define NRANGE 8
#define K4B 3128                               // 8 x 391 (3125 tiles + 3 idle)

typedef __bf16 bf16x8 __attribute__((ext_vector_type(8)));
typedef float  f32x4  __attribute__((ext_vector_type(4)));
typedef float  f32x2  __attribute__((ext_vector_type(2)));

__device__ __forceinline__ float waveReduceSum(float v) {
    #pragma unroll
    for (int off = 32; off > 0; off >>= 1) v += __shfl_xor(v, off, 64);
    return v;
}
__device__ __forceinline__ float waveReduceMax(float v) {
    #pragma unroll
    for (int off = 32; off > 0; off >>= 1) v = fmaxf(v, __shfl_xor(v, off, 64));
    return v;
}
__device__ __forceinline__ unsigned short f2bf(float x) {
    unsigned u = __float_as_uint(x);
    return (unsigned short)((u + 0x7FFFu + ((u >> 16) & 1u)) >> 16);
}
__device__ __forceinline__ float bf_lo(unsigned u) { return __uint_as_float(u << 16); }
__device__ __forceinline__ float bf_hi(unsigned u) { return __uint_as_float(u & 0xFFFF0000u); }
__device__ __forceinline__ int lane_prefix(unsigned long long m) {
    return __builtin_amdgcn_mbcnt_hi((unsigned)(m >> 32),
           __builtin_amdgcn_mbcnt_lo((unsigned)m, 0));
}

#define PKACC(u) { \
    c0 += (f32x2){bf_lo((u).x), bf_hi((u).x)}; \
    c1 += (f32x2){bf_lo((u).y), bf_hi((u).y)}; \
    c2 += (f32x2){bf_lo((u).z), bf_hi((u).z)}; \
    c3 += (f32x2){bf_lo((u).w), bf_hi((u).w)}; }

// ka2: zero topicsumR/loss + build all MFMA B-frags. grid 1400.
__global__ __launch_bounds__(256) void ka2_init(
        const float* __restrict__ alpha, const float* __restrict__ W1,
        const float* __restrict__ Wmu, const float* __restrict__ Wlv,
        unsigned short* __restrict__ bfrag, unsigned short* __restrict__ w1frag,
        unsigned short* __restrict__ wfrag, float* __restrict__ topicsumR,
        float* __restrict__ loss) {
    const int gid = blockIdx.x * 256 + threadIdx.x;
    if (gid < 512) topicsumR[gid] = 0.f;
    if (gid == 520) *loss = 0.f;
    if (gid < 4 * 10 * 64 * 8) {
        int j = gid & 7;
        int lane = (gid >> 3) & 63;
        int rest = gid >> 9;               // w*10 + kt
        int kt = rest % 10, w = rest / 10;
        int t = 16 * w + (lane & 15);
        int e = kt * 32 + (lane >> 4) * 8 + j;
        bfrag[gid] = (t < Tn && e < En) ? f2bf(alpha[t * En + e]) : (unsigned short)0;
    }
    if (gid < W1FRAG_N) {
        int j = gid & 7, lane = (gid >> 3) & 63, rest = gid >> 9;
        int kt = rest % 10, nt = rest / 10;
        int e = kt * 32 + (lane >> 4) * 8 + j;
        int hcol = nt * 16 + (lane & 15);
        w1frag[gid] = (e < En) ? f2bf(W1[e * Hn + hcol]) : (unsigned short)0;
    } else {
        int g2 = gid - W1FRAG_N;
        if (g2 < WFRAG_N) {
            int j = g2 & 7, lane = (g2 >> 3) & 63, rest = g2 >> 9;
            int kt = rest % 25, nt = rest / 25;
            int k = kt * 32 + (lane >> 4) * 8 + j;        // < 800 always
            int t = (nt & 3) * 16 + (lane & 15);
            float val = 0.f;
            if (t < Tn) val = (nt < 4) ? Wmu[k * Tn + t] : Wlv[k * Tn + t];
            wfrag[g2] = f2bf(val);
        }
    }
}

// kb4: fused cast+beta per 16-vocab tile, XCD-affine. grid K4B=3128.
__global__ __launch_bounds__(256) void kb4_beta(
        const float* __restrict__ rho, unsigned short* __restrict__ rhoh,
        const unsigned short* __restrict__ bfrag,
        unsigned int* __restrict__ betaU32, float* __restrict__ topicsumR) {
    __shared__ __align__(16) unsigned short xs[16 * 328];   // 10496 B A-tile
    __shared__ unsigned short trans[16 * 66];               // 2112 B
    const int x = blockIdx.x & 7;            // XCD == slice
    const int n = blockIdx.x >> 3;           // 0..390
    const int tile = ((x * 3125) >> 3) + n;
    if (tile >= (((x + 1) * 3125) >> 3)) return;
    const int tid = threadIdx.x;
    const int wave = tid >> 6, lane = tid & 63;
    const int quad = lane >> 4, l15 = lane & 15;
    const int v0 = tile * 16;
    // stage: 16 rows x 300 f32 -> bf16 LDS (pad cols 300..319 with 0)
    for (int i = tid; i < 16 * 80; i += 256) {      // 80 float4-slots/row
        int row = i / 80, s4 = i - row * 80;
        ushort4 o = {0, 0, 0, 0};
        if (s4 < 75) {
            float4 r = *(const float4*)(rho + (size_t)(v0 + row) * En + s4 * 4);
            o.x = f2bf(r.x); o.y = f2bf(r.y); o.z = f2bf(r.z); o.w = f2bf(r.w);
        }
        *(ushort4*)&xs[row * 328 + s4 * 4] = o;
    }
    __syncthreads();
    // persist the bf16 tile to rhoh (coalesced 16B stores; write-allocates
    // this XCD's L2 slice, which kb1 on the same XCD re-reads ~10x)
    for (int i = tid; i < 16 * 40; i += 256) {
        int row = i / 40, c8 = (i - row * 40) * 8;
        *(uint4*)(rhoh + (size_t)(v0 + row) * KP + c8) = *(const uint4*)&xs[row * 328 + c8];
    }
    // betaU tile: wave = topic tile
    const unsigned short* arow = xs + l15 * 328 + quad * 8;
    f32x4 acc = {0.f, 0.f, 0.f, 0.f};
    #pragma unroll
    for (int kt = 0; kt < 10; ++kt) {
        bf16x8 a = *(const bf16x8*)(arow + kt * 32);
        bf16x8 bv = *(const bf16x8*)(bfrag + ((wave * 10 + kt) * 64 + lane) * 8);
        acc = __builtin_amdgcn_mfma_f32_16x16x32_bf16(a, bv, acc, 0, 0, 0);
    }
    float ts = 0.f;
    #pragma unroll
    for (int r = 0; r < 4; ++r) {
        float ev = expf(acc[r]);
        ts += ev;
        trans[(quad * 4 + r) * 66 + 16 * wave + l15] = f2bf(ev);
    }
    ts += __shfl_xor(ts, 16, 64);
    ts += __shfl_xor(ts, 32, 64);
    const int t = 16 * wave + l15;
    if (lane < 16 && t < Tn)
        atomicAdd(&topicsumR[x * 64 + t], ts);       // replica == XCD
    __syncthreads();
    unsigned int* dst = betaU32 + (size_t)v0 * 32;
    const unsigned int* tr32 = (const unsigned int*)trans;
    for (int i = tid; i < 16 * 32; i += 256)
        dst[i] = tr32[(i >> 5) * 33 + (i & 31)];
}

// kb1: sliced token gather. grid Bn*NRANGE = 8192; r = bid%8 == XCD.
__global__ __launch_bounds__(256) void kb1_gather(
        const unsigned short* __restrict__ rhoh, const int* __restrict__ ids,
        int* __restrict__ toks, int* __restrict__ cnt,
        float* __restrict__ xbarP) {
    __shared__ __align__(16) int sid[Sn];
    __shared__ int sfid[Sn];
    __shared__ __align__(16) float xred[4][320];
    __shared__ int scount, sfull;
    const int tid = threadIdx.x;
    const int wave = tid >> 6, lane = tid & 63;
    const int r = blockIdx.x & (NRANGE - 1), b = blockIdx.x >> 3;
    const int lo = ((r * 3125) >> 3) * 16;
    const int hi = (((r + 1) * 3125) >> 3) * 16;
    if (tid == 0) { scount = 0; sfull = 0; }
    __syncthreads();
    #pragma unroll
    for (int s0 = 0; s0 < Sn; s0 += 256) {
        int id = __builtin_nontemporal_load(&ids[b * Sn + s0 + tid]);
        bool val = (id != 1 && id != 2);
        bool inr = val && id >= lo && id < hi;
        unsigned long long mb = __ballot(inr);
        int pre = lane_prefix(mb);
        int wc = __popcll(mb);
        int base = 0;
        if (lane == 0 && wc) base = atomicAdd(&scount, wc);
        base = __shfl(base, 0, 64);
        if (inr) sid[base + pre] = id;
        if (r == 0) {
            unsigned long long fb = __ballot(val);
            int fpre = lane_prefix(fb);
            int fwc = __popcll(fb);
            int fbase = 0;
            if (lane == 0 && fwc) fbase = atomicAdd(&sfull, fwc);
            fbase = __shfl(fbase, 0, 64);
            if (val) sfid[fbase + fpre] = id;
        }
    }
    __syncthreads();
    if (r == 0) {
        const int nf = sfull;
        for (int i = tid; i < nf; i += 256) toks[b * Sn + i] = sfid[i];
        if (tid == 0) cnt[b] = nf;
    }
    const int m = scount;
    f32x2 c0 = {0.f, 0.f}, c1 = {0.f, 0.f}, c2 = {0.f, 0.f}, c3 = {0.f, 0.f};
    if (lane < 40) {
        const uint4* rb = (const uint4*)rhoh;
        int s = wave;
        for (; s + 12 < m; s += 16) {
            int i0 = sid[s], i1 = sid[s + 4], i2 = sid[s + 8], i3 = sid[s + 12];
            uint4 u0 = rb[(size_t)i0 * 40 + lane];
            uint4 u1 = rb[(size_t)i1 * 40 + lane];
            uint4 u2 = rb[(size_t)i2 * 40 + lane];
            uint4 u3 = rb[(size_t)i3 * 40 + lane];
            PKACC(u0); PKACC(u1); PKACC(u2); PKACC(u3);
        }
        for (; s < m; s += 4) {
            uint4 u = rb[(size_t)sid[s] * 40 + lane];
            PKACC(u);
        }
        float* xw = &xred[wave][lane * 8];
        *(float4*)(xw)     = (float4){c0[0], c0[1], c1[0], c1[1]};
        *(float4*)(xw + 4) = (float4){c2[0], c2[1], c3[0], c3[1]};
    }
    __syncthreads();
    float* xbp = xbarP + ((size_t)b * NRANGE + r) * KP;
    for (int c = tid; c < KP; c += 256)
        xbp[c] = xred[0][c] + xred[1][c] + xred[2][c] + xred[3][c];
}

// ktail: fused kx+k2m+k3, one block per 16 docs. grid 64.
__global__ __launch_bounds__(256) void ktail(
        const float* __restrict__ xbarP, const int* __restrict__ cnt,
        const unsigned short* __restrict__ w1frag, const float* __restrict__ b1,
        const unsigned short* __restrict__ wfrag,
        const float* __restrict__ bmu, const float* __restrict__ blv,
        float* __restrict__ theta, float* __restrict__ loss) {
    __shared__ unsigned short xs[16 * 328];    // 10496 B
    __shared__ unsigned short hs[16 * 808];    // 25856 B
    __shared__ float mlds[16 * 65];
    __shared__ float llds[16 * 65];
    __shared__ float invn[16];
    const int tid = threadIdx.x;
    const int wave = tid >> 6, lane = tid & 63;
    const int quad = lane >> 4, l15 = lane & 15;
    const int b0 = blockIdx.x * 16;
    if (tid < 16) invn[tid] = 1.0f / (float)cnt[b0 + tid];
    __syncthreads();
    for (int i = tid; i < 16 * (KP / 4); i += 256) {
        int row = i / (KP / 4), e4 = (i - row * (KP / 4)) * 4;
        const float* bp = xbarP + ((size_t)(b0 + row) * NRANGE) * KP + e4;
        float sx = 0.f, sy = 0.f, sz = 0.f, sw_ = 0.f;
        #pragma unroll
        for (int rr = 0; rr < NRANGE; ++rr) {
            float4 v = *(const float4*)(bp + rr * KP);
            sx += v.x; sy += v.y; sz += v.z; sw_ += v.w;
        }
        float in = invn[row];
        ushort4 o;
        o.x = f2bf(sx * in); o.y = f2bf(sy * in);
        o.z = f2bf(sz * in); o.w = f2bf(sw_ * in);
        *(ushort4*)&xs[row * 328 + e4] = o;
    }
    __syncthreads();
    {
        const unsigned short* arow = xs + l15 * 328 + quad * 8;
        for (int nt = wave; nt < 50; nt += 4) {
            f32x4 acc = {0.f, 0.f, 0.f, 0.f};
            #pragma unroll
            for (int kt = 0; kt < 10; ++kt) {
                bf16x8 a = *(const bf16x8*)(arow + kt * 32);
                bf16x8 bv = *(const bf16x8*)(w1frag + ((size_t)(nt * 10 + kt) * 64 + lane) * 8);
                acc = __builtin_amdgcn_mfma_f32_16x16x32_bf16(a, bv, acc, 0, 0, 0);
            }
            const int col = nt * 16 + l15;
            const float bias = b1[col];
            #pragma unroll
            for (int r = 0; r < 4; ++r)
                hs[(quad * 4 + r) * 808 + col] = f2bf(fmaxf(acc[r] + bias, 0.f));
        }
    }
    __syncthreads();
    {
        const unsigned short* arow = hs + l15 * 808 + quad * 8;
        f32x4 am = {0.f, 0.f, 0.f, 0.f}, al = {0.f, 0.f, 0.f, 0.f};
        #pragma unroll
        for (int kt = 0; kt < 25; ++kt) {
            bf16x8 a  = *(const bf16x8*)(arow + kt * 32);
            bf16x8 bm = *(const bf16x8*)(wfrag + ((size_t)(wave * 25 + kt) * 64 + lane) * 8);
            bf16x8 bl = *(const bf16x8*)(wfrag + ((size_t)((4 + wave) * 25 + kt) * 64 + lane) * 8);
            am = __builtin_amdgcn_mfma_f32_16x16x32_bf16(a, bm, am, 0, 0, 0);
            al = __builtin_amdgcn_mfma_f32_16x16x32_bf16(a, bl, al, 0, 0, 0);
        }
        const int t = wave * 16 + l15;
        const float bm_ = (t < Tn) ? bmu[t] : 0.f;
        const float bl_ = (t < Tn) ? blv[t] : 0.f;
        #pragma unroll
        for (int r = 0; r < 4; ++r) {
            int row = quad * 4 + r;
            mlds[row * 65 + t] = am[r] + bm_;
            llds[row * 65 + t] = al[r] + bl_;
        }
    }
    __syncthreads();
    const int tt = (lane < Tn) ? lane : (Tn - 1);
    const bool act = (lane < Tn);
    float klacc = 0.f;
    #pragma unroll
    for (int k = 0; k < 4; ++k) {
        int row = wave * 4 + k;
        float mu = mlds[row * 65 + tt];
        float lv = llds[row * 65 + tt];
        float m = waveReduceMax(act ? mu : -1e30f);
        float ex = act ? expf(mu - m) : 0.f;
        float ssum = waveReduceSum(ex);
        if (act) theta[(b0 + row) * Tn + lane] = ex / ssum;
        klacc += waveReduceSum(act ? (1.f + lv - mu * mu - expf(lv)) : 0.f);
    }
    if (lane == 0) atomicAdd(loss, -0.5f * klacc * (1.0f / (float)Bn));
}

// k6: recon loss. grid Bn.
__global__ __launch_bounds__(256) void k6_recon(
        const int* __restrict__ toks, const int* __restrict__ cnt,
        const float* __restrict__ theta, const float* __restrict__ topicsumR,
        const unsigned short* __restrict__ betaUh, float* __restrict__ loss) {
    __shared__ float sw[Tn];
    __shared__ float swred[4];
    const int b = blockIdx.x, tid = threadIdx.x;
    if (tid < Tn) {
        float z = 0.f;
        #pragma unroll
        for (int j = 0; j < 8; ++j) z += topicsumR[j * 64 + tid];
        sw[tid] = theta[b * Tn + tid] / z;
    }
    __syncthreads();
    float wr[Tn];
    #pragma unroll
    for (int t = 0; t < Tn; ++t) wr[t] = sw[t];
    float lsum = 0.f;
    const int n = cnt[b];
    for (int i = tid; i < n; i += 256) {
        int v = toks[b * Sn + i];
        const uint4* q = (const uint4*)(betaUh + (size_t)v * BSTR);
        float dot = 0.f;
        #pragma unroll
        for (int k = 0; k < 6; ++k) {
            uint4 u = q[k];
            int t = 8 * k;
            dot += wr[t]     * bf_lo(u.x) + wr[t + 1] * bf_hi(u.x);
            dot += wr[t + 2] * bf_lo(u.y) + wr[t + 3] * bf_hi(u.y);
            dot += wr[t + 4] * bf_lo(u.z) + wr[t + 5] * bf_hi(u.z);
            dot += wr[t + 6] * bf_lo(u.w) + wr[t + 7] * bf_hi(u.w);
        }
        unsigned d = ((const unsigned*)q)[24];
        dot += wr[48] * bf_lo(d) + wr[49] * bf_hi(d);
        lsum += logf(dot + 1e-5f);
    }
    float s = waveReduceSum(lsum);
    const int wave = tid >> 6, lane = tid & 63;
    if (lane == 0) swred[wave] = s;
    __syncthreads();
    if (tid == 0) {
        float tot = swred[0] + swred[1] + swred[2] + swred[3];
        atomicAdd(loss, -tot * (1.0f / (float)Bn));
    }
}

extern "C" void kernel_launch(void* const* d_in, const int* in_sizes, int n_in,
                              void* d_out, int out_size, void* d_ws, size_t ws_size,
                              hipStream_t stream) {
    const int*   ids   = (const int*)d_in[0];
    const float* rho   = (const float*)d_in[1];
    const float* alpha = (const float*)d_in[2];
    const float* W1    = (const float*)d_in[3];
    const float* b1    = (const float*)d_in[4];
    const float* Wmu   = (const float*)d_in[5];
    const float* bmu   = (const float*)d_in[6];
    const float* Wlv   = (const float*)d_in[7];
    const float* blv   = (const float*)d_in[8];

    float* theta = (float*)d_out;            // [B, T]
    float* loss  = theta + Bn * Tn;          // scalar at d_out[51200]

    char* w = (char*)d_ws;
    float* topicsumR = (float*)w;               w += 8 * 64 * 4;
    unsigned short* bfrag = (unsigned short*)w; w += 4 * 10 * 64 * 8 * 2;
    unsigned short* w1frag = (unsigned short*)w; w += (size_t)W1FRAG_N * 2;
    unsigned short* wfrag = (unsigned short*)w;  w += (size_t)WFRAG_N * 2;
    int*   cnt      = (int*)w;                  w += Bn * 4;
    int*   toks     = (int*)w;                  w += Bn * Sn * 4;
    float* xbarP    = (float*)w;                w += (size_t)Bn * NRANGE * KP * 4; // 10.5 MB
    unsigned short* rhoh = (unsigned short*)w;  w += (size_t)Vn * KP * 2;   // 32 MB
    unsigned int* betaU32 = (unsigned int*)w;   w += (size_t)Vn * 128;      // 6.4 MB

    const int k0grid = (W1FRAG_N + WFRAG_N + 255) / 256;   // 1400
    ka2_init<<<k0grid, 256, 0, stream>>>(
        alpha, W1, Wmu, Wlv, bfrag, w1frag, wfrag, topicsumR, loss);
    kb4_beta<<<K4B, 256, 0, stream>>>(rho, rhoh, bfrag, betaU32, topicsumR);
    kb1_gather<<<Bn * NRANGE, 256, 0, stream>>>(rhoh, ids, toks, cnt, xbarP);
    ktail<<<64, 256, 0, stream>>>(xbarP, cnt, w1frag, b1, wfrag, bmu, blv,
                                  theta, loss);
    k6_recon<<<Bn, 256, 0, stream>>>(toks, cnt, theta, topicsumR,
                                     (const unsigned short*)betaU32, loss);
}